// Round 6
// baseline (102.582 us; speedup 1.0000x reference)
//
#include <hip/hip_runtime.h>
#include <hip/hip_bf16.h>
#include <math.h>

#define NPIX 4096

typedef __attribute__((ext_vector_type(8))) short s8;    // 8 x bf16 (4 VGPRs)
typedef __attribute__((ext_vector_type(16))) float f16v; // 16 x f32 (32x32 acc)

typedef __attribute__((address_space(1))) const void glob_cv;
typedef __attribute__((address_space(3))) void lds_v;

static __device__ __forceinline__ unsigned packbf2(float a, float b) {
    union { __hip_bfloat162 h; unsigned u; } x;
    x.h = __float22bfloat162_rn(make_float2(a, b));
    return x.u;
}
static __device__ __forceinline__ float fexp2(float x) {
#if __has_builtin(__builtin_amdgcn_exp2f)
    return __builtin_amdgcn_exp2f(x);
#else
    return exp2f(x);
#endif
}

// async global->LDS 16B: HW writes lane l at (wave-uniform lds base) + l*16.
static __device__ __forceinline__ void gl_lds16(const unsigned short* g,
                                                unsigned short* l, int lane) {
#if __has_builtin(__builtin_amdgcn_global_load_lds)
    __builtin_amdgcn_global_load_lds((glob_cv*)g, (lds_v*)l, 16, 0, 0);
#else
    *(uint4*)(l + lane * 8) = *(const uint4*)g;   // correctness fallback (sync)
#endif
}

// Half-swap of two regs across the lane<32 / lane>=32 boundary.
static __device__ __forceinline__ void lane_swap(unsigned a, unsigned b, int lh,
                                                 unsigned &x, unsigned &y) {
#if __has_builtin(__builtin_amdgcn_permlane32_swap)
    auto r = __builtin_amdgcn_permlane32_swap((int)a, (int)b, false, false);
    x = (unsigned)r[0];
    y = (unsigned)r[1];
#else
    unsigned sa = __shfl_xor(a, 32), sb = __shfl_xor(b, 32);
    x = lh ? sb : a;
    y = lh ? b : sa;
#endif
}

// ---------------------------------------------------------------------------
// Kernel 1: prep v2 (unchanged; R3-R5 passed). NOTE: prep-attributed time did
// not move between v1 (256 blk) and v2 (512 blk) -> much of the ~28us residual
// is suspected harness reset dispatches, not this kernel. Left untouched.
// ---------------------------------------------------------------------------
__global__ __launch_bounds__(512) void prep_kernel(
    const float* __restrict__ x,
    const float* __restrict__ Wq, const float* __restrict__ bq,
    const float* __restrict__ Wk, const float* __restrict__ bk,
    __hip_bfloat16* __restrict__ qbf, __hip_bfloat16* __restrict__ kbf,
    __hip_bfloat16* __restrict__ xbf)
{
    __shared__ float Xp[64][65];
    __shared__ unsigned short Qs[64][8];
    int t = threadIdx.x;
    int p = t & 63;                  // pixel lane
    int g = t >> 6;                  // 0..7 = output channel (wave-uniform)
    int bid = blockIdx.x;
    int og = bid & 1;                // 0: q, 1: k
    int n0 = ((bid >> 1) & 63) << 6;
    int b  = bid >> 7;

    const float* xb = x + ((size_t)b << 18);
    __hip_bfloat16* xbb = xbf + ((size_t)b << 18);
#pragma unroll
    for (int u = 0; u < 8; ++u) {
        int c = g + (u << 3);
        float v = xb[((size_t)c << 12) + n0 + p];
        Xp[c][p] = v;
        if ((og == 0) ? (u < 4) : (u >= 4))   // split conversion halves
            xbb[((size_t)c << 12) + n0 + p] = __float2bfloat16(v);
    }
    __syncthreads();

    const float* W  = og ? Wk : Wq;
    const float* bb = og ? bk : bq;
    const float* wr = W + g * 64;            // wave-uniform row
    float acc = bb[g];
#pragma unroll
    for (int c = 0; c < 64; ++c) acc = fmaf(wr[c], Xp[c][p], acc);
    if (!og) acc *= 1.4426950408889634f;     // fold log2(e) into q

    union { __hip_bfloat16 h; unsigned short u; } cv;
    cv.h = __float2bfloat16(acc);
    Qs[p][g] = cv.u;
    __syncthreads();

    if (t < 64) {
        __hip_bfloat16* dst = (og ? kbf : qbf) + ((size_t)(b * NPIX + n0 + t) << 3);
        *(s8*)dst = *(const s8*)&Qs[t][0];   // coalesced 16B per pixel
    }
}

// ---------------------------------------------------------------------------
// Kernel 2: fused flash, R6 structure — ZERO main-loop barriers.
// R5 audit: busy ~1300 cyc/SIMD/tile (trans 512, VALU 384, LDS 256, mat 160)
// vs ~3500 wall => 72% stall = barrier-lockstep convoy (8 waves burst the
// same pipe phase together, 16x per block). Fix: waves stop sharing tiles.
// Each wave owns contiguous j-range [w*512,(w+1)*512) as 16 sub-tiles of
// 32 j; stages its own X[64 c][32 j] (4 KB) into a PRIVATE double-buffered
// LDS region (8 KB/wave, 64 KB/block) via 4x global_load_lds, synced with
// wave-local counted `s_waitcnt vmcnt(4)` (+sched_barrier(0), rule #18).
// Count safety: only our 4 in-order DMAs counted; vmcnt retires oldest-
// first, so compiler-moved kf loads can only make the wait stricter. Last
// 2 iterations peel to vmcnt(4)/vmcnt(0). Waves free-run & self-stagger.
// LDS granule swizzle g^((row>>1)&3): inverse-swizzled GLOBAL source +
// same XOR on read (rule #21); PV reads become b128, worst 2-way (free).
// Score/softmax/lane_swap-PV/epilogue math identical to R4/R5 (passed).
// ---------------------------------------------------------------------------
__global__ __launch_bounds__(512, 4) void flash_fused_kernel(
    const __hip_bfloat16* __restrict__ qbf, const __hip_bfloat16* __restrict__ kbf,
    const __hip_bfloat16* __restrict__ xbf,
    const float* __restrict__ Wv, const float* __restrict__ bv,
    const float* __restrict__ x, const float* __restrict__ gamma,
    float* __restrict__ out)
{
    // main loop: wave w owns pool[w*8192 .. w*8192+8191]: 2 x 4096 B buffers,
    //   each [64 rows][4 granules of 16 B], granule-XOR-swizzled.
    // epilogue overlay (all after a full __syncthreads): OshA [32][68] @0 |
    //   OshB @8704 | Linv @17408 | bvs @17536 | Wvs @17792 (16384) | Lsh @34176
    __shared__ __align__(16) char pool[65536];

    int t = threadIdx.x;
    int w    = t >> 6;               // 0..7 = j-range owner (wave-uniform)
    int lane = t & 63;
    int l32  = lane & 31;
    int lh   = lane >> 5;

    int b  = blockIdx.x >> 7;
    int i0 = (blockIdx.x & 127) << 5;

    const s8 zero8 = {0, 0, 0, 0, 0, 0, 0, 0};

    // Q B-frag: B[k=lh*8+r -> d][n=l32 -> i=i0+l32]; lh=1 half zeroed (d<8)
    s8 qf;
    {
        s8 qv = *(const s8*)(qbf + ((size_t)(b * NPIX + i0 + l32) << 3));
        qf = (lh == 0) ? qv : zero8;
    }

    f16v acc[2];                      // acc[cm]: O[c=cm*32+row(r,lh)][i=l32]
    f16v zero16;
#pragma unroll
    for (int r = 0; r < 16; ++r) { acc[0][r] = 0.f; acc[1][r] = 0.f; zero16[r] = 0.f; }
    float lsum = 0.f;

    const __hip_bfloat16* kb = kbf + ((size_t)(b * NPIX) << 3) + ((size_t)(w << 9) << 3);
    const unsigned short* xg = (const unsigned short*)xbf + ((size_t)b << 18);

    unsigned short* mybuf = (unsigned short*)pool + (w << 12);  // 8192 B/wave

    // DMA u (0..3): lane l -> row = 16u + (l>>2), phys granule l&3, sourced
    // from global granule (l&3)^swz(row), swz = (row>>1)&3. Linear LDS dest.
    int l2 = lane >> 2, lg = lane & 3;
    int srcb[4];                      // shorts; + n*32 per sub-tile
#pragma unroll
    for (int u = 0; u < 4; ++u) {
        int row = (u << 4) + l2;
        srcb[u] = (row << 12) + (w << 9) + ((lg ^ ((row >> 1) & 3)) << 3);
    }
    // PV b128 read offsets (shorts, loop-invariant): row cm*32+l32,
    // logical granule {lh, 2+lh} -> phys ^ swz; swz same for cm=0/1.
    int sw = (l32 >> 1) & 3;
    int o00 = (l32 << 5) + ((lh ^ sw) << 3);
    int o01 = (l32 << 5) + (((2 + lh) ^ sw) << 3);
    int o10 = ((32 + l32) << 5) + ((lh ^ sw) << 3);
    int o11 = ((32 + l32) << 5) + (((2 + lh) ^ sw) << 3);

#define STAGE(BO, N) do {                                                    \
        unsigned short* lb_ = mybuf + (BO);                                  \
        _Pragma("unroll")                                                    \
        for (int u_ = 0; u_ < 4; ++u_)                                       \
            gl_lds16(xg + srcb[u_] + ((N) << 5), lb_ + (u_ << 9), lane);     \
    } while (0)

#define WAITN(N) do {                                                        \
        asm volatile("s_waitcnt vmcnt(" #N ")" ::: "memory");                \
        __builtin_amdgcn_sched_barrier(0);                                   \
    } while (0)

#define BODY(BO, KF) do {                                                    \
        f16v sC = __builtin_amdgcn_mfma_f32_32x32x16_bf16(KF, qf, zero16, 0, 0, 0); \
        float e_[16];                                                        \
        _Pragma("unroll")                                                    \
        for (int r_ = 0; r_ < 16; ++r_) e_[r_] = fexp2(sC[r_]);              \
        _Pragma("unroll")                                                    \
        for (int r_ = 0; r_ < 16; ++r_) lsum += e_[r_];                      \
        unsigned P2[8];                                                      \
        _Pragma("unroll")                                                    \
        for (int s_ = 0; s_ < 8; ++s_) P2[s_] = packbf2(e_[2*s_], e_[2*s_+1]); \
        unsigned b00,b01,b02,b03,b10,b11,b12,b13;                            \
        lane_swap(P2[0], P2[2], lh, b00, b02);                               \
        lane_swap(P2[1], P2[3], lh, b01, b03);                               \
        lane_swap(P2[4], P2[6], lh, b10, b12);                               \
        lane_swap(P2[5], P2[7], lh, b11, b13);                               \
        union { unsigned u[4]; s8 v; } bf0, bf1;                             \
        bf0.u[0]=b00; bf0.u[1]=b01; bf0.u[2]=b02; bf0.u[3]=b03;              \
        bf1.u[0]=b10; bf1.u[1]=b11; bf1.u[2]=b12; bf1.u[3]=b13;              \
        const unsigned short* xb_ = mybuf + (BO);                            \
        s8 xa;                                                               \
        xa = *(const s8*)(xb_ + o00);                                        \
        acc[0] = __builtin_amdgcn_mfma_f32_32x32x16_bf16(xa, bf0.v, acc[0], 0, 0, 0); \
        xa = *(const s8*)(xb_ + o01);                                        \
        acc[0] = __builtin_amdgcn_mfma_f32_32x32x16_bf16(xa, bf1.v, acc[0], 0, 0, 0); \
        xa = *(const s8*)(xb_ + o10);                                        \
        acc[1] = __builtin_amdgcn_mfma_f32_32x32x16_bf16(xa, bf0.v, acc[1], 0, 0, 0); \
        xa = *(const s8*)(xb_ + o11);                                        \
        acc[1] = __builtin_amdgcn_mfma_f32_32x32x16_bf16(xa, bf1.v, acc[1], 0, 0, 0); \
    } while (0)

    // prologue: sub-tiles 0,1 -> buffers 0,1; k frags for 0,1
    STAGE(0, 0);
    STAGE(2048, 1);
    s8 kfA = *(const s8*)(kb + ((size_t)l32 << 3));
    s8 kfB = *(const s8*)(kb + ((size_t)(32 + l32) << 3));

    for (int n = 0; n < 14; n += 2) {
        WAITN(4);                     // sub-tile n landed (n+1's 4 DMAs allowed)
        BODY(0, kfA);
        STAGE(0, n + 2);
        kfA = *(const s8*)(kb + ((size_t)(((n + 2) << 5) + l32) << 3));
        WAITN(4);                     // sub-tile n+1 landed
        BODY(2048, kfB);
        STAGE(2048, n + 3);
        kfB = *(const s8*)(kb + ((size_t)(((n + 3) << 5) + l32) << 3));
    }
    WAITN(4);                         // sub-tile 14 landed (15's DMAs allowed)
    BODY(0, kfA);
    WAITN(0);                         // sub-tile 15 landed (nothing newer)
    BODY(2048, kfB);
#undef BODY
#undef WAITN
#undef STAGE

    // ---------------- epilogue (cross-wave; barriers resume here) ----------
    float* OshA = (float*)pool;                  // [32 i][68]
    float* OshB = (float*)(pool + 8704);         // [32 i][68]
    float* Linv = (float*)(pool + 17408);        // [32]
    float* bvs  = (float*)(pool + 17536);        // [64]
    float* Wvs  = (float*)(pool + 17792);        // [64][64]
    float* Lsh  = (float*)(pool + 34176);        // [8][32]

    lsum += __shfl_xor(lsum, 32);                // full 512-j range sum per i
    __syncthreads();                 // ALL waves done with private regions
    if (lh == 0) Lsh[w * 32 + l32] = lsum;

    // 2-tree stripe reduction: waves 0-3 -> OshA, waves 4-7 -> OshB
    float* Og = (w >> 2) ? OshB : OshA;
    for (int s = 0; s < 4; ++s) {
        __syncthreads();
        if ((w & 3) == s) {
#pragma unroll
            for (int cm = 0; cm < 2; ++cm)
#pragma unroll
                for (int r = 0; r < 16; ++r) {
                    int cc = cm * 32 + (r & 3) + 8 * (r >> 2) + 4 * lh;
                    float* p = Og + l32 * 68 + cc;
                    if (s == 0) *p = acc[cm][r];
                    else        *p += acc[cm][r];
                }
        }
    }
    __syncthreads();

    // stage Linv / bv / Wv
    if (t < 32) {
        float lt = 0.f;
#pragma unroll
        for (int ww = 0; ww < 8; ++ww) lt += Lsh[ww * 32 + t];
        Linv[t] = 1.0f / lt;
    }
    if (t < 64) bvs[t] = bv[t];
    {
        const float4* wsrc = (const float4*)Wv;
        float4* wdst = (float4*)Wvs;
        wdst[t] = wsrc[t];
        wdst[t + 512] = wsrc[t + 512];
    }
    __syncthreads();

    // projection + residual: i = t&31, cg = t>>5 (0..15) -> 4 channels each
    {
        int i  = t & 31;
        int cg = t >> 5;
        float inv = Linv[i];
        float res[4] = {0.f, 0.f, 0.f, 0.f};
#pragma unroll 4
        for (int cb = 0; cb < 16; ++cb) {
            float4 oa = *(const float4*)(OshA + i * 68 + cb * 4);
            float4 ob = *(const float4*)(OshB + i * 68 + cb * 4);
            float4 o = make_float4(oa.x + ob.x, oa.y + ob.y, oa.z + ob.z, oa.w + ob.w);
#pragma unroll
            for (int k = 0; k < 4; ++k) {
                const float4 wv4 = *(const float4*)(Wvs + (cg * 4 + k) * 64 + cb * 4);
                res[k] = fmaf(wv4.x, o.x, fmaf(wv4.y, o.y, fmaf(wv4.z, o.z, fmaf(wv4.w, o.w, res[k]))));
            }
        }
        float g = gamma[0];
        const float* xr = x + ((size_t)b << 18) + i0;
        float* outp = out + ((size_t)b << 18) + i0;
#pragma unroll
        for (int k = 0; k < 4; ++k) {
            int cch = cg * 4 + k;
            float attn = fmaf(res[k], inv, bvs[cch]);
            size_t off = ((size_t)cch << 12) + i;
            outp[off] = fmaf(g, attn, xr[off]);
        }
    }
}

extern "C" void kernel_launch(void* const* d_in, const int* in_sizes, int n_in,
                              void* d_out, int out_size, void* d_ws, size_t ws_size,
                              hipStream_t stream) {
    const float* x     = (const float*)d_in[0];
    const float* Wq    = (const float*)d_in[1];
    const float* bq    = (const float*)d_in[2];
    const float* Wk    = (const float*)d_in[3];
    const float* bk    = (const float*)d_in[4];
    const float* Wv    = (const float*)d_in[5];
    const float* bv    = (const float*)d_in[6];
    const float* gamma = (const float*)d_in[7];
    float* out = (float*)d_out;

    // ws: qbf 256KB | kbf 256KB | xbf 2MB
    __hip_bfloat16* qbf = (__hip_bfloat16*)d_ws;
    __hip_bfloat16* kbf = qbf + (size_t)4 * NPIX * 8;
    __hip_bfloat16* xbf = kbf + (size_t)4 * NPIX * 8;

    prep_kernel<<<512, 512, 0, stream>>>(x, Wq, bq, Wk, bk, qbf, kbf, xbf);
    flash_fused_kernel<<<512, 512, 0, stream>>>(qbf, kbf, xbf, Wv, bv, x, gamma, out);
}

// Round 7
// 99.839 us; speedup vs baseline: 1.0275x; 1.0275x over previous
//
#include <hip/hip_runtime.h>
#include <hip/hip_bf16.h>
#include <math.h>

#define NPIX 4096

typedef __attribute__((ext_vector_type(8))) short s8;    // 8 x bf16 (4 VGPRs)
typedef __attribute__((ext_vector_type(16))) float f16v; // 16 x f32 (32x32 acc)

typedef __attribute__((address_space(1))) const void glob_cv;
typedef __attribute__((address_space(3))) void lds_v;

static __device__ __forceinline__ unsigned packbf2(float a, float b) {
    union { __hip_bfloat162 h; unsigned u; } x;
    x.h = __float22bfloat162_rn(make_float2(a, b));
    return x.u;
}
static __device__ __forceinline__ float fexp2(float x) {
#if __has_builtin(__builtin_amdgcn_exp2f)
    return __builtin_amdgcn_exp2f(x);
#else
    return exp2f(x);
#endif
}

// async global->LDS 16B: HW writes lane l at (wave-uniform lds base) + l*16.
static __device__ __forceinline__ void gl_lds16(const unsigned short* g,
                                                unsigned short* l, int lane) {
#if __has_builtin(__builtin_amdgcn_global_load_lds)
    __builtin_amdgcn_global_load_lds((glob_cv*)g, (lds_v*)l, 16, 0, 0);
#else
    *(uint4*)(l + lane * 8) = *(const uint4*)g;   // correctness fallback (sync)
#endif
}

// Half-swap of two regs across the lane<32 / lane>=32 boundary.
static __device__ __forceinline__ void lane_swap(unsigned a, unsigned b, int lh,
                                                 unsigned &x, unsigned &y) {
#if __has_builtin(__builtin_amdgcn_permlane32_swap)
    auto r = __builtin_amdgcn_permlane32_swap((int)a, (int)b, false, false);
    x = (unsigned)r[0];
    y = (unsigned)r[1];
#else
    unsigned sa = __shfl_xor(a, 32), sb = __shfl_xor(b, 32);
    x = lh ? sb : a;
    y = lh ? b : sa;
#endif
}

// ---------------------------------------------------------------------------
// Kernel 1: prep v2 (unchanged; R3-R6 passed).
// ---------------------------------------------------------------------------
__global__ __launch_bounds__(512) void prep_kernel(
    const float* __restrict__ x,
    const float* __restrict__ Wq, const float* __restrict__ bq,
    const float* __restrict__ Wk, const float* __restrict__ bk,
    __hip_bfloat16* __restrict__ qbf, __hip_bfloat16* __restrict__ kbf,
    __hip_bfloat16* __restrict__ xbf)
{
    __shared__ float Xp[64][65];
    __shared__ unsigned short Qs[64][8];
    int t = threadIdx.x;
    int p = t & 63;                  // pixel lane
    int g = t >> 6;                  // 0..7 = output channel (wave-uniform)
    int bid = blockIdx.x;
    int og = bid & 1;                // 0: q, 1: k
    int n0 = ((bid >> 1) & 63) << 6;
    int b  = bid >> 7;

    const float* xb = x + ((size_t)b << 18);
    __hip_bfloat16* xbb = xbf + ((size_t)b << 18);
#pragma unroll
    for (int u = 0; u < 8; ++u) {
        int c = g + (u << 3);
        float v = xb[((size_t)c << 12) + n0 + p];
        Xp[c][p] = v;
        if ((og == 0) ? (u < 4) : (u >= 4))   // split conversion halves
            xbb[((size_t)c << 12) + n0 + p] = __float2bfloat16(v);
    }
    __syncthreads();

    const float* W  = og ? Wk : Wq;
    const float* bb = og ? bk : bq;
    const float* wr = W + g * 64;            // wave-uniform row
    float acc = bb[g];
#pragma unroll
    for (int c = 0; c < 64; ++c) acc = fmaf(wr[c], Xp[c][p], acc);
    if (!og) acc *= 1.4426950408889634f;     // fold log2(e) into q

    union { __hip_bfloat16 h; unsigned short u; } cv;
    cv.h = __float2bfloat16(acc);
    Qs[p][g] = cv.u;
    __syncthreads();

    if (t < 64) {
        __hip_bfloat16* dst = (og ? kbf : qbf) + ((size_t)(b * NPIX + n0 + t) << 3);
        *(s8*)dst = *(const s8*)&Qs[t][0];   // coalesced 16B per pixel
    }
}

// ---------------------------------------------------------------------------
// Kernel 2: fused flash, R7 = R6 skeleton + two fixes:
//  FIX 1 (counted waits): R6's WAITN(4) sat right after issuing {4 DMA + kf}
//    = 5 outstanding -> retired the oldest = a JUST-issued DMA: every
//    sub-tile stalled a full memory latency (same net effect as R5's
//    vmcnt(0)-in-barrier; explains R5==R6==31us). Now each sched-region
//    issues exactly 5 VMEM ops {kf, 4 DMA}; WAITN(5) at region entry waits
//    only on loads issued one full BODY earlier. sched_barrier(0) fences
//    make the region count a compiler-proof invariant (any within-region
//    reorder keeps 5). Tail: WAITN(5) then WAITN(0).
//  FIX 2 (XCD swizzle, bijective since 512%8==0): lbid=(bid&7)*64+(bid>>3)
//    gives each XCD 64 contiguous logical blocks = ONE batch's xbf (2MB)
//    + kbf (64KB) -> fits 4MB per-XCD L2. Default round-robin gave every
//    XCD an 8MB working set -> L3-latency loads (~700cy) that a 1-body
//    wait distance can't cover.
// Math (score/softmax/lane_swap PV/epilogue) identical to R4-R6 (passed).
// ---------------------------------------------------------------------------
__global__ __launch_bounds__(512, 4) void flash_fused_kernel(
    const __hip_bfloat16* __restrict__ qbf, const __hip_bfloat16* __restrict__ kbf,
    const __hip_bfloat16* __restrict__ xbf,
    const float* __restrict__ Wv, const float* __restrict__ bv,
    const float* __restrict__ x, const float* __restrict__ gamma,
    float* __restrict__ out)
{
    // main loop: wave w owns pool[w*8192 .. +8191]: 2 x 4096 B buffers,
    //   each [64 rows][4 granules of 16 B], granule-XOR-swizzled.
    // epilogue overlay (after full __syncthreads): OshA [32][68] @0 |
    //   OshB @8704 | Linv @17408 | bvs @17536 | Wvs @17792 (16384) | Lsh @34176
    __shared__ __align__(16) char pool[65536];

    int t = threadIdx.x;
    int w    = t >> 6;               // 0..7 = j-range owner (wave-uniform)
    int lane = t & 63;
    int l32  = lane & 31;
    int lh   = lane >> 5;

    // FIX 2: bijective XCD-contiguous remap (8 XCDs, 512 blocks)
    int bid  = blockIdx.x;
    int lbid = ((bid & 7) << 6) + (bid >> 3);
    int b  = lbid >> 7;
    int i0 = (lbid & 127) << 5;

    const s8 zero8 = {0, 0, 0, 0, 0, 0, 0, 0};

    // Q B-frag: B[k=lh*8+r -> d][n=l32 -> i=i0+l32]; lh=1 half zeroed (d<8)
    s8 qf;
    {
        s8 qv = *(const s8*)(qbf + ((size_t)(b * NPIX + i0 + l32) << 3));
        qf = (lh == 0) ? qv : zero8;
    }

    f16v acc[2];                      // acc[cm]: O[c=cm*32+row(r,lh)][i=l32]
    f16v zero16;
#pragma unroll
    for (int r = 0; r < 16; ++r) { acc[0][r] = 0.f; acc[1][r] = 0.f; zero16[r] = 0.f; }
    float lsum = 0.f;

    const __hip_bfloat16* kb = kbf + ((size_t)(b * NPIX) << 3) + ((size_t)(w << 9) << 3);
    const unsigned short* xg = (const unsigned short*)xbf + ((size_t)b << 18);

    unsigned short* mybuf = (unsigned short*)pool + (w << 12);  // 8192 B/wave

    // DMA u (0..3): lane l -> row = 16u + (l>>2), phys granule l&3, sourced
    // from global granule (l&3)^swz(row), swz = (row>>1)&3. Linear LDS dest.
    int l2 = lane >> 2, lg = lane & 3;
    int srcb[4];                      // shorts; + n*32 per sub-tile
#pragma unroll
    for (int u = 0; u < 4; ++u) {
        int row = (u << 4) + l2;
        srcb[u] = (row << 12) + (w << 9) + ((lg ^ ((row >> 1) & 3)) << 3);
    }
    // PV b128 read offsets (shorts, loop-invariant): row cm*32+l32,
    // logical granule {lh, 2+lh} -> phys ^ swz; swz same for cm=0/1.
    int sw = (l32 >> 1) & 3;
    int o00 = (l32 << 5) + ((lh ^ sw) << 3);
    int o01 = (l32 << 5) + (((2 + lh) ^ sw) << 3);
    int o10 = ((32 + l32) << 5) + ((lh ^ sw) << 3);
    int o11 = ((32 + l32) << 5) + (((2 + lh) ^ sw) << 3);

#define STAGE(BO, N) do {                                                    \
        unsigned short* lb_ = mybuf + (BO);                                  \
        _Pragma("unroll")                                                    \
        for (int u_ = 0; u_ < 4; ++u_)                                       \
            gl_lds16(xg + srcb[u_] + ((N) << 5), lb_ + (u_ << 9), lane);     \
    } while (0)

#define WAITN(N) do {                                                        \
        asm volatile("s_waitcnt vmcnt(" #N ")" ::: "memory");                \
        __builtin_amdgcn_sched_barrier(0);                                   \
    } while (0)

#define BODY(BO, KF) do {                                                    \
        f16v sC = __builtin_amdgcn_mfma_f32_32x32x16_bf16(KF, qf, zero16, 0, 0, 0); \
        float e_[16];                                                        \
        _Pragma("unroll")                                                    \
        for (int r_ = 0; r_ < 16; ++r_) e_[r_] = fexp2(sC[r_]);              \
        _Pragma("unroll")                                                    \
        for (int r_ = 0; r_ < 16; ++r_) lsum += e_[r_];                      \
        unsigned P2[8];                                                      \
        _Pragma("unroll")                                                    \
        for (int s_ = 0; s_ < 8; ++s_) P2[s_] = packbf2(e_[2*s_], e_[2*s_+1]); \
        unsigned b00,b01,b02,b03,b10,b11,b12,b13;                            \
        lane_swap(P2[0], P2[2], lh, b00, b02);                               \
        lane_swap(P2[1], P2[3], lh, b01, b03);                               \
        lane_swap(P2[4], P2[6], lh, b10, b12);                               \
        lane_swap(P2[5], P2[7], lh, b11, b13);                               \
        union { unsigned u[4]; s8 v; } bf0, bf1;                             \
        bf0.u[0]=b00; bf0.u[1]=b01; bf0.u[2]=b02; bf0.u[3]=b03;              \
        bf1.u[0]=b10; bf1.u[1]=b11; bf1.u[2]=b12; bf1.u[3]=b13;              \
        const unsigned short* xb_ = mybuf + (BO);                            \
        s8 xa;                                                               \
        xa = *(const s8*)(xb_ + o00);                                        \
        acc[0] = __builtin_amdgcn_mfma_f32_32x32x16_bf16(xa, bf0.v, acc[0], 0, 0, 0); \
        xa = *(const s8*)(xb_ + o01);                                        \
        acc[0] = __builtin_amdgcn_mfma_f32_32x32x16_bf16(xa, bf1.v, acc[0], 0, 0, 0); \
        xa = *(const s8*)(xb_ + o10);                                        \
        acc[1] = __builtin_amdgcn_mfma_f32_32x32x16_bf16(xa, bf0.v, acc[1], 0, 0, 0); \
        xa = *(const s8*)(xb_ + o11);                                        \
        acc[1] = __builtin_amdgcn_mfma_f32_32x32x16_bf16(xa, bf1.v, acc[1], 0, 0, 0); \
    } while (0)

    // prologue region: {qf above} + kfA, A0x4, kfB, B1x4 issued; first wait
    // retires qf+kfA+A0 (compiler adds its own qf-dependency wait if needed).
    s8 kfA = *(const s8*)(kb + ((size_t)l32 << 3));
    STAGE(0, 0);
    s8 kfB = *(const s8*)(kb + ((size_t)(32 + l32) << 3));
    STAGE(2048, 1);

    // steady state: every region issues exactly 5 VMEM ops {kf, 4 DMA};
    // WAITN(5) == "all regions before the previous one are retired".
    for (int n = 0; n < 14; n += 2) {
        WAITN(5);                     // A(n) + kfA(n) landed (staged 1 body ago)
        BODY(0, kfA);
        kfA = *(const s8*)(kb + ((size_t)(((n + 2) << 5) + l32) << 3));
        STAGE(0, n + 2);
        WAITN(5);                     // B(n+1) + kfB(n+1) landed
        BODY(2048, kfB);
        kfB = *(const s8*)(kb + ((size_t)(((n + 3) << 5) + l32) << 3));
        STAGE(2048, n + 3);
    }
    WAITN(5);                         // A(14) landed (B(15) batch still allowed)
    BODY(0, kfA);
    WAITN(0);                         // B(15) landed
    BODY(2048, kfB);
#undef BODY
#undef WAITN
#undef STAGE

    // ---------------- epilogue (cross-wave; barriers resume here) ----------
    float* OshA = (float*)pool;                  // [32 i][68]
    float* OshB = (float*)(pool + 8704);         // [32 i][68]
    float* Linv = (float*)(pool + 17408);        // [32]
    float* bvs  = (float*)(pool + 17536);        // [64]
    float* Wvs  = (float*)(pool + 17792);        // [64][64]
    float* Lsh  = (float*)(pool + 34176);        // [8][32]

    lsum += __shfl_xor(lsum, 32);                // full 512-j range sum per i
    __syncthreads();                 // ALL waves done with private regions
    if (lh == 0) Lsh[w * 32 + l32] = lsum;

    // 2-tree stripe reduction: waves 0-3 -> OshA, waves 4-7 -> OshB
    float* Og = (w >> 2) ? OshB : OshA;
    for (int s = 0; s < 4; ++s) {
        __syncthreads();
        if ((w & 3) == s) {
#pragma unroll
            for (int cm = 0; cm < 2; ++cm)
#pragma unroll
                for (int r = 0; r < 16; ++r) {
                    int cc = cm * 32 + (r & 3) + 8 * (r >> 2) + 4 * lh;
                    float* p = Og + l32 * 68 + cc;
                    if (s == 0) *p = acc[cm][r];
                    else        *p += acc[cm][r];
                }
        }
    }
    __syncthreads();

    // stage Linv / bv / Wv
    if (t < 32) {
        float lt = 0.f;
#pragma unroll
        for (int ww = 0; ww < 8; ++ww) lt += Lsh[ww * 32 + t];
        Linv[t] = 1.0f / lt;
    }
    if (t < 64) bvs[t] = bv[t];
    {
        const float4* wsrc = (const float4*)Wv;
        float4* wdst = (float4*)Wvs;
        wdst[t] = wsrc[t];
        wdst[t + 512] = wsrc[t + 512];
    }
    __syncthreads();

    // projection + residual: i = t&31, cg = t>>5 (0..15) -> 4 channels each
    {
        int i  = t & 31;
        int cg = t >> 5;
        float inv = Linv[i];
        float res[4] = {0.f, 0.f, 0.f, 0.f};
#pragma unroll 4
        for (int cb = 0; cb < 16; ++cb) {
            float4 oa = *(const float4*)(OshA + i * 68 + cb * 4);
            float4 ob = *(const float4*)(OshB + i * 68 + cb * 4);
            float4 o = make_float4(oa.x + ob.x, oa.y + ob.y, oa.z + ob.z, oa.w + ob.w);
#pragma unroll
            for (int k = 0; k < 4; ++k) {
                const float4 wv4 = *(const float4*)(Wvs + (cg * 4 + k) * 64 + cb * 4);
                res[k] = fmaf(wv4.x, o.x, fmaf(wv4.y, o.y, fmaf(wv4.z, o.z, fmaf(wv4.w, o.w, res[k]))));
            }
        }
        float g = gamma[0];
        const float* xr = x + ((size_t)b << 18) + i0;
        float* outp = out + ((size_t)b << 18) + i0;
#pragma unroll
        for (int k = 0; k < 4; ++k) {
            int cch = cg * 4 + k;
            float attn = fmaf(res[k], inv, bvs[cch]);
            size_t off = ((size_t)cch << 12) + i;
            outp[off] = fmaf(g, attn, xr[off]);
        }
    }
}

extern "C" void kernel_launch(void* const* d_in, const int* in_sizes, int n_in,
                              void* d_out, int out_size, void* d_ws, size_t ws_size,
                              hipStream_t stream) {
    const float* x     = (const float*)d_in[0];
    const float* Wq    = (const float*)d_in[1];
    const float* bq    = (const float*)d_in[2];
    const float* Wk    = (const float*)d_in[3];
    const float* bk    = (const float*)d_in[4];
    const float* Wv    = (const float*)d_in[5];
    const float* bv    = (const float*)d_in[6];
    const float* gamma = (const float*)d_in[7];
    float* out = (float*)d_out;

    // ws: qbf 256KB | kbf 256KB | xbf 2MB
    __hip_bfloat16* qbf = (__hip_bfloat16*)d_ws;
    __hip_bfloat16* kbf = qbf + (size_t)4 * NPIX * 8;
    __hip_bfloat16* xbf = kbf + (size_t)4 * NPIX * 8;

    prep_kernel<<<512, 512, 0, stream>>>(x, Wq, bq, Wk, bk, qbf, kbf, xbf);
    flash_fused_kernel<<<512, 512, 0, stream>>>(qbf, kbf, xbf, Wv, bv, x, gamma, out);
}